// Round 5
// baseline (583.684 us; speedup 1.0000x reference)
//
#include <hip/hip_runtime.h>
#include <hip/hip_bf16.h>
#include <math.h>

#define B_ 2048
#define N_ 512
#define D_ 128
#define H_ 256
#define G0f 1e-4f   // repair margin: ~10x the bf16x3 max score error
#define GRID_MLP 1024

typedef __attribute__((ext_vector_type(8))) short bf16x8;
typedef __attribute__((ext_vector_type(4))) short short4v;
typedef __attribute__((ext_vector_type(4))) float f32x4;

__device__ __forceinline__ short f2bf(float x) {          // rne f32 -> bf16
    unsigned u = __float_as_uint(x);
    u = u + 0x7fffu + ((u >> 16) & 1u);
    return (short)(u >> 16);
}
__device__ __forceinline__ float bf2f(short h) {
    return __uint_as_float(((unsigned)(unsigned short)h) << 16);
}

// ---------------- W1 pre-pack: fragment-ordered bf16 hi/lo ----------------
__global__ __launch_bounds__(256) void pack_w(const float* __restrict__ W1,
                                              short* __restrict__ WpH,
                                              short* __restrict__ WpL)
{
    int tid = blockIdx.x * 256 + threadIdx.x;   // 0..4095
    int l  = tid & 63;
    int ks = (tid >> 6) & 3;
    int nf = tid >> 8;
    int n  = nf * 16 + (l & 15);
    int kb = ks * 32 + ((l >> 4) << 3);
    bf16x8 hi, lo;
    #pragma unroll
    for (int j = 0; j < 8; ++j) {
        float w = W1[(size_t)(kb + j) * H_ + n];
        short h = f2bf(w);
        hi[j] = h;
        lo[j] = f2bf(w - bf2f(h));
    }
    *(bf16x8*)&WpH[(size_t)tid * 8] = hi;
    *(bf16x8*)&WpL[(size_t)tid * 8] = lo;
}

// ---------------- MLP via bf16x3 MFMA — persistent, register-prefetch pipeline ----------------
// 1024 blocks x 256 thr (4 waves) = 4 blocks/CU. Each block: 16 tiles of 64 rows.
__global__ __launch_bounds__(256, 2) void mlp_mfma(
    const float* __restrict__ X, const short* __restrict__ WpH,
    const short* __restrict__ WpL, const float* __restrict__ b1,
    const float* __restrict__ W2, const float* __restrict__ b2,
    float* __restrict__ ls)
{
    __shared__ short Xh[64 * 128];
    __shared__ short Xl[64 * 128];
    __shared__ float zl[256];

    const int t    = threadIdx.x;
    const int lane = t & 63;
    const int wn   = t >> 6;

    const bf16x8* WH = (const bf16x8*)WpH;
    const bf16x8* WL = (const bf16x8*)WpL;

    bf16x8 Bhi[4][4];                           // resident B-hi (64 VGPR)
    #pragma unroll
    for (int q = 0; q < 4; ++q)
        #pragma unroll
        for (int ks = 0; ks < 4; ++ks)
            Bhi[q][ks] = WH[((wn * 4 + q) * 4 + ks) * 64 + lane];

    float b1v[4], w2v[4];
    #pragma unroll
    for (int q = 0; q < 4; ++q) {
        int c = wn * 64 + q * 16 + (lane & 15);
        b1v[q] = b1[c];
        w2v[q] = W2[c];
    }
    const float b2v = b2[0];

    const int NT = (B_ * N_ / 64) / GRID_MLP;   // 16 tiles per block
    int tile = blockIdx.x;

    float4 pf[8];                               // prefetch registers (32 VGPR)
    {
        const float4* Xg = (const float4*)(X + (size_t)tile * 64 * D_);
        #pragma unroll
        for (int i = 0; i < 8; ++i) pf[i] = Xg[t + i * 256];
    }

    size_t m_prev = 0;

    for (int it = 0; it < NT; ++it) {
        const size_t m0 = (size_t)tile * 64;
        const int ntile = tile + GRID_MLP;

        __syncthreads();                        // (a) LDS X free; zl(prev tile) complete

        if (it > 0 && t < 64) {                 // deferred epilogue (reads zl only)
            float z = zl[t] + zl[64 + t] + zl[128 + t] + zl[192 + t] + b2v;
            ls[m_prev + t] = 1.f / (1.f + expf(-z)) - 0.5f;
        }

        // convert pf -> LDS (waits on the loads issued last iteration)
        #pragma unroll
        for (int i = 0; i < 8; ++i) {
            int f = t + i * 256;
            int row = f >> 5, k0 = (f & 31) << 2;
            float xv[4] = {pf[i].x, pf[i].y, pf[i].z, pf[i].w};
            short4v hv, lv;
            #pragma unroll
            for (int j = 0; j < 4; ++j) {
                short h = f2bf(xv[j]);
                hv[j] = h;
                lv[j] = f2bf(xv[j] - bf2f(h));
            }
            int sidx = (row * 128 + k0) ^ ((row & 7) << 3);
            *(short4v*)&Xh[sidx] = hv;
            *(short4v*)&Xl[sidx] = lv;
        }

        if (it + 1 < NT) {                      // issue next tile's loads (latency hides under MFMA)
            const float4* Xg = (const float4*)(X + (size_t)ntile * 64 * D_);
            #pragma unroll
            for (int i = 0; i < 8; ++i) pf[i] = Xg[t + i * 256];
        }

        __syncthreads();                        // (b) X tile visible

        f32x4 acc[4][4];
        #pragma unroll
        for (int mf = 0; mf < 4; ++mf)
            #pragma unroll
            for (int q = 0; q < 4; ++q)
                acc[mf][q] = (f32x4){0.f, 0.f, 0.f, 0.f};

        #pragma unroll
        for (int ks = 0; ks < 4; ++ks) {
            bf16x8 Blo[4];
            #pragma unroll
            for (int q = 0; q < 4; ++q)
                Blo[q] = WL[((wn * 4 + q) * 4 + ks) * 64 + lane];
            #pragma unroll
            for (int mf = 0; mf < 4; ++mf) {
                int r = mf * 16 + (lane & 15);
                int sidx = (r * 128 + ks * 32 + ((lane >> 4) << 3)) ^ ((r & 7) << 3);
                bf16x8 Ah = *(const bf16x8*)&Xh[sidx];
                bf16x8 Al = *(const bf16x8*)&Xl[sidx];
                #pragma unroll
                for (int q = 0; q < 4; ++q) {
                    acc[mf][q] = __builtin_amdgcn_mfma_f32_16x16x32_bf16(Ah, Bhi[q][ks], acc[mf][q], 0, 0, 0);
                    acc[mf][q] = __builtin_amdgcn_mfma_f32_16x16x32_bf16(Al, Bhi[q][ks], acc[mf][q], 0, 0, 0);
                    acc[mf][q] = __builtin_amdgcn_mfma_f32_16x16x32_bf16(Ah, Blo[q],     acc[mf][q], 0, 0, 0);
                }
            }
        }

        // z partials -> zl (read after next barrier (a))
        #pragma unroll
        for (int mf = 0; mf < 4; ++mf) {
            #pragma unroll
            for (int i = 0; i < 4; ++i) {
                float zz = 0.f;
                #pragma unroll
                for (int q = 0; q < 4; ++q) {
                    float h = acc[mf][q][i] + b1v[q];
                    h = h > 0.f ? h : 0.f;
                    zz += h * w2v[q];
                }
                zz += __shfl_xor(zz, 1, 64);
                zz += __shfl_xor(zz, 2, 64);
                zz += __shfl_xor(zz, 4, 64);
                zz += __shfl_xor(zz, 8, 64);
                if ((lane & 15) == 0) zl[wn * 64 + mf * 16 + ((lane >> 4) << 2) + i] = zz;
            }
        }

        m_prev = m0;
        tile = ntile;
    }

    __syncthreads();
    if (t < 64) {
        float z = zl[t] + zl[64 + t] + zl[128 + t] + zl[192 + t] + b2v;
        ls[m_prev + t] = 1.f / (1.f + expf(-z)) - 0.5f;
    }
}

// ---------------- radix-select machinery (ballot-based, no DS ops) ----------------
__device__ __forceinline__ unsigned f2key(float f) {      // monotone float->uint
    unsigned u = __float_as_uint(f);
    return (u & 0x80000000u) ? ~u : (u | 0x80000000u);
}
__device__ __forceinline__ float key2f(unsigned k) {
    return __uint_as_float((k & 0x80000000u) ? (k & 0x7fffffffu) : ~k);
}
__device__ __forceinline__ int lane_lt_count(unsigned long long m) {
    return __builtin_amdgcn_mbcnt_hi((unsigned)(m >> 32),
           __builtin_amdgcn_mbcnt_lo((unsigned)m, 0));
}

// wave-wide top-k threshold over 8 slots/lane: T = key of k-th largest, need = #ties to take
__device__ __forceinline__ void radix_topk(const unsigned (&key)[8], int k,
                                           unsigned &T, int &need)
{
    unsigned prefix = 0, maskhi = 0;
    int kk = k;
    for (int bit = 31; bit >= 0; --bit) {
        unsigned b = 1u << bit;
        int cnt1 = 0;
        #pragma unroll
        for (int j = 0; j < 8; ++j) {
            bool one = ((key[j] & maskhi) == prefix) && (key[j] & b);
            cnt1 += __popcll(__ballot(one));
        }
        if (cnt1 >= kk) prefix |= b; else kk -= cnt1;
        maskhi |= b;
    }
    T = prefix; need = kk;
}

// membership with lowest-global-index tiebreak; slot order n = l + 64*j => rank by (j, lane)
__device__ __forceinline__ void tie_member(const unsigned (&key)[8], unsigned T,
                                           int need, bool (&mem)[8])
{
    int base = 0;
    #pragma unroll
    for (int j = 0; j < 8; ++j) {
        unsigned long long eb = __ballot(key[j] == T);
        int r = base + lane_lt_count(eb);
        mem[j] = (key[j] > T) || ((key[j] == T) && (r < need));
        base += __popcll(eb);
    }
}

// ---------------- selection: 1 wave/row radix fast path, block-coop exact repair ----------------
__global__ __launch_bounds__(256) void select_kernel(
    const float* __restrict__ ls, const float* __restrict__ spread,
    const float* __restrict__ vol, const float* __restrict__ X,
    const float* __restrict__ W1, const float* __restrict__ b1,
    const float* __restrict__ W2, const float* __restrict__ b2,
    float* __restrict__ action, float* __restrict__ conf_out)
{
    __shared__ int   s_uidx[4][50];
    __shared__ float s_xrow[50][128];
    __shared__ float s_mabs[512];
    __shared__ float s_val[512];
    __shared__ int   s_flag[4];
    __shared__ int   s_cnt[4];

    const int t = threadIdx.x;
    const int l = t & 63;
    const int w = t >> 6;
    const int b = blockIdx.x * 4 + w;
    const size_t base = (size_t)b * N_;

    if (t < 4) s_cnt[t] = 0;

    // ---------- fast path (wave-private, ballot-only) ----------
    float rv[8], lsv[8];
    unsigned kr[8];
    bool anyv = false;
    #pragma unroll
    for (int j = 0; j < 8; ++j) {
        int n = l + (j << 6);
        float sp = spread[base + n];
        float vo = vol[base + n];
        bool valid = isfinite(sp) && (sp > 0.f);
        rv[j]  = valid ? (vo / (sp + 1e-8f)) : -INFINITY;
        lsv[j] = ls[base + n];
        anyv |= valid;
        kr[j] = f2key(rv[j]);
    }
    bool allow_all = (__any((int)anyv) == 0);

    unsigned T50; int need50;
    radix_topk(kr, 50, T50, need50);
    bool mem50[8];
    tie_member(kr, T50, need50, mem50);

    float mabs[8];
    unsigned km[8];
    #pragma unroll
    for (int j = 0; j < 8; ++j) {
        bool u = allow_all || mem50[j];
        mabs[j] = u ? fabsf(lsv[j]) : -INFINITY;
        km[j] = f2key(mabs[j]);
    }
    unsigned T10; int need10;
    radix_topk(km, 10, T10, need10);
    bool mem10[8];
    tie_member(km, T10, need10, mem10);

    // one butterfly for (Z-sum, conf-max, b11-max)
    float zp = 0.f, cf = -INFINITY, bn = -INFINITY;
    #pragma unroll
    for (int j = 0; j < 8; ++j) {
        if (mem10[j]) zp += mabs[j];
        else          bn = fmaxf(bn, mabs[j]);   // universe-not-selected
        cf = fmaxf(cf, mabs[j]);
    }
    #pragma unroll
    for (int s = 1; s < 64; s <<= 1) {
        zp += __shfl_xor(zp, s, 64);
        cf = fmaxf(cf, __shfl_xor(cf, s, 64));
        bn = fmaxf(bn, __shfl_xor(bn, s, 64));
    }
    float conf = cf;
    float b10 = key2f(T10);
    float b11 = bn;

    bool flag = (b10 - b11 < G0f) || (fabsf(conf - 0.05f) < G0f);

    if (!flag) {
        float cfin  = isfinite(conf) ? conf : 0.f;
        float scale = (cfin >= 0.05f) ? (1.f / (zp + 1e-8f)) : 0.f;
        #pragma unroll
        for (int j = 0; j < 8; ++j) {
            int n = l + (j << 6);
            action[base + n] = mem10[j] ? lsv[j] * scale : 0.f;
        }
        if (l == 0) conf_out[b] = cfin;
    }
    if (l == 0) s_flag[w] = (flag ? 1 : 0) | (allow_all ? 2 : 0);
    __syncthreads();

    // build universe index list for own flagged row
    if ((s_flag[w] & 3) == 1) {
        #pragma unroll
        for (int j = 0; j < 8; ++j)
            if (mem50[j]) {
                int p = atomicAdd(&s_cnt[w], 1);
                s_uidx[w][p] = l + (j << 6);
            }
    }
    __syncthreads();

    // ---------- exact fp32 repair, block-cooperative ----------
    for (int r = 0; r < 4; ++r) {
        int fl = s_flag[r];
        if (!(fl & 1)) continue;
        bool allow = (fl & 2) != 0;
        int U = allow ? 512 : 50;
        int brow = blockIdx.x * 4 + r;
        size_t rbase = (size_t)brow * N_;

        s_mabs[t] = -INFINITY; s_mabs[t + 256] = -INFINITY;
        s_val[t]  = 0.f;       s_val[t + 256]  = 0.f;

        if (!allow) {
            #pragma unroll
            for (int a0 = 0; a0 < 56; a0 += 8) {
                int a = a0 + (t >> 5);
                if (a < 50) {
                    int asset = s_uidx[r][a];
                    const float4* src = (const float4*)(X + (rbase + asset) * D_);
                    ((float4*)&s_xrow[a][0])[t & 31] = src[t & 31];
                }
            }
        }
        __syncthreads();

        float4 b1v = *(const float4*)&b1[l * 4];
        float4 w2v = *(const float4*)&W2[l * 4];
        for (int a = w; a < U; a += 4) {
            int asset = allow ? a : s_uidx[r][a];
            float h0 = 0.f, h1 = 0.f, h2 = 0.f, h3 = 0.f;
            if (!allow) {
                #pragma unroll 8
                for (int k = 0; k < D_; ++k) {
                    float xk = s_xrow[a][k];
                    float4 wv = *(const float4*)&W1[(size_t)k * H_ + l * 4];
                    h0 += xk * wv.x; h1 += xk * wv.y; h2 += xk * wv.z; h3 += xk * wv.w;
                }
            } else {
                const float* xr = X + (rbase + asset) * D_;
                #pragma unroll 8
                for (int k = 0; k < D_; ++k) {
                    float xk = xr[k];
                    float4 wv = *(const float4*)&W1[(size_t)k * H_ + l * 4];
                    h0 += xk * wv.x; h1 += xk * wv.y; h2 += xk * wv.z; h3 += xk * wv.w;
                }
            }
            h0 += b1v.x; h1 += b1v.y; h2 += b1v.z; h3 += b1v.w;
            float zpz = (h0 > 0.f ? h0 : 0.f) * w2v.x + (h1 > 0.f ? h1 : 0.f) * w2v.y
                      + (h2 > 0.f ? h2 : 0.f) * w2v.z + (h3 > 0.f ? h3 : 0.f) * w2v.w;
            #pragma unroll
            for (int s = 1; s < 64; s <<= 1) zpz += __shfl_xor(zpz, s, 64);
            if (l == 0) {
                float v = 1.f / (1.f + expf(-(zpz + b2[0]))) - 0.5f;
                s_mabs[asset] = fabsf(v);
                s_val[asset]  = v;
            }
        }
        __syncthreads();

        if (w == r) {       // owner wave: exact top-10 via radix
            float m2[8], v2[8];
            unsigned k2[8];
            #pragma unroll
            for (int j = 0; j < 8; ++j) {
                m2[j] = s_mabs[l + (j << 6)];
                v2[j] = s_val[l + (j << 6)];
                k2[j] = f2key(m2[j]);
            }
            unsigned Tx; int needx;
            radix_topk(k2, 10, Tx, needx);
            bool memx[8];
            tie_member(k2, Tx, needx, memx);
            float zx = 0.f, cfx = -INFINITY;
            #pragma unroll
            for (int j = 0; j < 8; ++j) {
                if (memx[j]) zx += m2[j];
                cfx = fmaxf(cfx, m2[j]);
            }
            #pragma unroll
            for (int s = 1; s < 64; s <<= 1) {
                zx += __shfl_xor(zx, s, 64);
                cfx = fmaxf(cfx, __shfl_xor(cfx, s, 64));
            }
            cfx = isfinite(cfx) ? cfx : 0.f;
            float scale = (cfx >= 0.05f) ? (1.f / (zx + 1e-8f)) : 0.f;
            #pragma unroll
            for (int j = 0; j < 8; ++j) {
                int n = l + (j << 6);
                action[rbase + n] = memx[j] ? v2[j] * scale : 0.f;
            }
            if (l == 0) conf_out[brow] = cfx;
        }
        __syncthreads();
    }
}

extern "C" void kernel_launch(void* const* d_in, const int* in_sizes, int n_in,
                              void* d_out, int out_size, void* d_ws, size_t ws_size,
                              hipStream_t stream)
{
    const float* X  = (const float*)d_in[0];
    const float* sp = (const float*)d_in[1];
    const float* vo = (const float*)d_in[2];
    const float* W1 = (const float*)d_in[3];
    const float* b1 = (const float*)d_in[4];
    const float* W2 = (const float*)d_in[5];
    const float* b2 = (const float*)d_in[6];

    float* action = (float*)d_out;
    float* conf   = action + (size_t)B_ * N_;

    float* ls = (float*)d_ws;                       // 4 MB
    size_t need = (size_t)B_ * N_ * 4 + 2 * (size_t)D_ * H_ * 2;
    short *WpH, *WpL;
    if (ws_size >= need) {
        WpH = (short*)((char*)d_ws + (size_t)B_ * N_ * 4);
        WpL = WpH + (size_t)D_ * H_;
    } else {
        WpH = (short*)(action + (size_t)out_size - 2 * (size_t)D_ * H_ / 2);
        WpL = WpH + (size_t)D_ * H_;
    }

    hipLaunchKernelGGL(pack_w, dim3(16), dim3(256), 0, stream, W1, WpH, WpL);
    hipLaunchKernelGGL(mlp_mfma, dim3(GRID_MLP), dim3(256), 0, stream,
                       X, WpH, WpL, b1, W2, b2, ls);
    hipLaunchKernelGGL(select_kernel, dim3(B_ / 4), dim3(256), 0, stream,
                       ls, sp, vo, X, W1, b1, W2, b2, action, conf);
}

// Round 6
// 463.712 us; speedup vs baseline: 1.2587x; 1.2587x over previous
//
#include <hip/hip_runtime.h>
#include <hip/hip_bf16.h>
#include <math.h>

#define B_ 2048
#define N_ 512
#define D_ 128
#define H_ 256
#define BANDf 2e-4f   // repair band: >= 2x worst-case bf16x3 score error (~1e-5..5e-5)

typedef __attribute__((ext_vector_type(8))) short bf16x8;
typedef __attribute__((ext_vector_type(4))) short short4v;
typedef __attribute__((ext_vector_type(4))) float f32x4;

__device__ __forceinline__ short f2bf(float x) {          // rne f32 -> bf16
    unsigned u = __float_as_uint(x);
    u = u + 0x7fffu + ((u >> 16) & 1u);
    return (short)(u >> 16);
}
__device__ __forceinline__ float bf2f(short h) {
    return __uint_as_float(((unsigned)(unsigned short)h) << 16);
}

// ---------------- W1 pre-pack: fragment-ordered bf16 hi/lo ----------------
// B-frag (16x16x32): lane l holds B[k = ks*32 + (l>>4)*8 + j][n = nf*16 + (l&15)]
__global__ __launch_bounds__(256) void pack_w(const float* __restrict__ W1,
                                              short* __restrict__ WpH,
                                              short* __restrict__ WpL)
{
    int tid = blockIdx.x * 256 + threadIdx.x;   // 0..4095
    int l  = tid & 63;
    int ks = (tid >> 6) & 3;
    int nf = tid >> 8;
    int n  = nf * 16 + (l & 15);
    int kb = ks * 32 + ((l >> 4) << 3);
    bf16x8 hi, lo;
    #pragma unroll
    for (int j = 0; j < 8; ++j) {
        float w = W1[(size_t)(kb + j) * H_ + n];
        short h = f2bf(w);
        hi[j] = h;
        lo[j] = f2bf(w - bf2f(h));
    }
    *(bf16x8*)&WpH[(size_t)tid * 8] = hi;
    *(bf16x8*)&WpL[(size_t)tid * 8] = lo;
}

// ---------------- MLP via bf16x3 MFMA — 8-wave blocks, low-VGPR, streamed B ----------------
// 512 blocks x 512 thr (8 waves) = 2 blocks/CU, 16 waves/CU. Block tile 64 rows x 256 cols.
// Wave wn owns cols wn*32..+31 (q=0..1), rows 0..63 (mf=0..3). acc = 32 AGPR.
__global__ __launch_bounds__(512, 4) void mlp_mfma(
    const float* __restrict__ X, const short* __restrict__ WpH,
    const short* __restrict__ WpL, const float* __restrict__ b1,
    const float* __restrict__ W2, const float* __restrict__ b2,
    float* __restrict__ ls)
{
    __shared__ short Xh[64 * 128];
    __shared__ short Xl[64 * 128];
    __shared__ float zl[512];

    const int t    = threadIdx.x;
    const int lane = t & 63;
    const int wn   = t >> 6;

    const bf16x8* WH = (const bf16x8*)WpH;
    const bf16x8* WL = (const bf16x8*)WpL;

    float b1v[2], w2v[2];
    #pragma unroll
    for (int q = 0; q < 2; ++q) {
        int c = wn * 32 + q * 16 + (lane & 15);
        b1v[q] = b1[c];
        w2v[q] = W2[c];
    }
    const float b2v = b2[0];

    const int GRID = 512;
    const int NT = (B_ * N_ / 64) / GRID;       // 32 tiles per block
    int tile = blockIdx.x;

    float4 pf[4];                               // prefetch registers (16 VGPR)
    {
        const float4* Xg = (const float4*)(X + (size_t)tile * 64 * D_);
        #pragma unroll
        for (int i = 0; i < 4; ++i) pf[i] = Xg[t + i * 512];
    }

    size_t m_prev = 0;

    for (int it = 0; it < NT; ++it) {
        const size_t m0 = (size_t)tile * 64;
        const int ntile = tile + GRID;

        __syncthreads();                        // (a) LDS X free; zl(prev) complete

        if (it > 0 && t < 64) {                 // deferred epilogue (reads zl only)
            float z = b2v;
            #pragma unroll
            for (int w8 = 0; w8 < 8; ++w8) z += zl[w8 * 64 + t];
            ls[m_prev + t] = 1.f / (1.f + expf(-z)) - 0.5f;
        }

        // convert pf -> LDS (waits on loads issued last iteration)
        #pragma unroll
        for (int i = 0; i < 4; ++i) {
            int f = t + i * 512;
            int row = f >> 5, k0 = (f & 31) << 2;
            float xv[4] = {pf[i].x, pf[i].y, pf[i].z, pf[i].w};
            short4v hv, lv;
            #pragma unroll
            for (int j = 0; j < 4; ++j) {
                short h = f2bf(xv[j]);
                hv[j] = h;
                lv[j] = f2bf(xv[j] - bf2f(h));
            }
            int sidx = (row * 128 + k0) ^ ((row & 7) << 3);
            *(short4v*)&Xh[sidx] = hv;
            *(short4v*)&Xl[sidx] = lv;
        }

        // B(ks=0) preload FIRST (so its waitcnt doesn't drain the pf loads below)
        bf16x8 Bh[2][2], Bl[2][2];
        #pragma unroll
        for (int q = 0; q < 2; ++q) {
            Bh[0][q] = WH[((wn * 2 + q) * 4 + 0) * 64 + lane];
            Bl[0][q] = WL[((wn * 2 + q) * 4 + 0) * 64 + lane];
        }

        if (it + 1 < NT) {                      // issue next tile's X loads
            const float4* Xg = (const float4*)(X + (size_t)ntile * 64 * D_);
            #pragma unroll
            for (int i = 0; i < 4; ++i) pf[i] = Xg[t + i * 512];
        }

        __syncthreads();                        // (b) X tile visible

        f32x4 acc[4][2];
        #pragma unroll
        for (int mf = 0; mf < 4; ++mf)
            #pragma unroll
            for (int q = 0; q < 2; ++q)
                acc[mf][q] = (f32x4){0.f, 0.f, 0.f, 0.f};

        #pragma unroll
        for (int ks = 0; ks < 4; ++ks) {
            const int cur = ks & 1, nxt = cur ^ 1;
            if (ks < 3) {                       // pipeline next ks's B fragments
                #pragma unroll
                for (int q = 0; q < 2; ++q) {
                    Bh[nxt][q] = WH[((wn * 2 + q) * 4 + ks + 1) * 64 + lane];
                    Bl[nxt][q] = WL[((wn * 2 + q) * 4 + ks + 1) * 64 + lane];
                }
            }
            #pragma unroll
            for (int mf = 0; mf < 4; ++mf) {
                int r = mf * 16 + (lane & 15);
                int sidx = (r * 128 + ks * 32 + ((lane >> 4) << 3)) ^ ((r & 7) << 3);
                bf16x8 Ah = *(const bf16x8*)&Xh[sidx];
                bf16x8 Al = *(const bf16x8*)&Xl[sidx];
                #pragma unroll
                for (int q = 0; q < 2; ++q) {
                    acc[mf][q] = __builtin_amdgcn_mfma_f32_16x16x32_bf16(Ah, Bh[cur][q], acc[mf][q], 0, 0, 0);
                    acc[mf][q] = __builtin_amdgcn_mfma_f32_16x16x32_bf16(Al, Bh[cur][q], acc[mf][q], 0, 0, 0);
                    acc[mf][q] = __builtin_amdgcn_mfma_f32_16x16x32_bf16(Ah, Bl[cur][q], acc[mf][q], 0, 0, 0);
                }
            }
        }

        // z partials -> zl (read after next barrier (a))
        #pragma unroll
        for (int mf = 0; mf < 4; ++mf) {
            #pragma unroll
            for (int i = 0; i < 4; ++i) {
                float zz = 0.f;
                #pragma unroll
                for (int q = 0; q < 2; ++q) {
                    float h = acc[mf][q][i] + b1v[q];
                    h = h > 0.f ? h : 0.f;
                    zz += h * w2v[q];
                }
                zz += __shfl_xor(zz, 1, 64);
                zz += __shfl_xor(zz, 2, 64);
                zz += __shfl_xor(zz, 4, 64);
                zz += __shfl_xor(zz, 8, 64);
                if ((lane & 15) == 0) zl[wn * 64 + mf * 16 + ((lane >> 4) << 2) + i] = zz;
            }
        }

        m_prev = m0;
        tile = ntile;
    }

    __syncthreads();
    if (t < 64) {
        float z = b2v;
        #pragma unroll
        for (int w8 = 0; w8 < 8; ++w8) z += zl[w8 * 64 + t];
        ls[m_prev + t] = 1.f / (1.f + expf(-z)) - 0.5f;
    }
}

// ---------------- radix-select machinery (ballot-based, no DS ops) ----------------
__device__ __forceinline__ unsigned f2key(float f) {      // monotone float->uint
    unsigned u = __float_as_uint(f);
    return (u & 0x80000000u) ? ~u : (u | 0x80000000u);
}
__device__ __forceinline__ float key2f(unsigned k) {
    return __uint_as_float((k & 0x80000000u) ? (k & 0x7fffffffu) : ~k);
}
__device__ __forceinline__ int lane_lt_count(unsigned long long m) {
    return __builtin_amdgcn_mbcnt_hi((unsigned)(m >> 32),
           __builtin_amdgcn_mbcnt_lo((unsigned)m, 0));
}

__device__ __forceinline__ void radix_topk(const unsigned (&key)[8], int k,
                                           unsigned &T, int &need)
{
    unsigned prefix = 0, maskhi = 0;
    int kk = k;
    for (int bit = 31; bit >= 0; --bit) {
        unsigned b = 1u << bit;
        int cnt1 = 0;
        #pragma unroll
        for (int j = 0; j < 8; ++j) {
            bool one = ((key[j] & maskhi) == prefix) && (key[j] & b);
            cnt1 += __popcll(__ballot(one));
        }
        if (cnt1 >= kk) prefix |= b; else kk -= cnt1;
        maskhi |= b;
    }
    T = prefix; need = kk;
}

// membership, lowest-global-index tiebreak (slot n = l + 64*j => rank by (j, lane))
__device__ __forceinline__ void tie_member(const unsigned (&key)[8], unsigned T,
                                           int need, bool (&mem)[8])
{
    int base = 0;
    #pragma unroll
    for (int j = 0; j < 8; ++j) {
        unsigned long long eb = __ballot(key[j] == T);
        int r = base + lane_lt_count(eb);
        mem[j] = (key[j] > T) || ((key[j] == T) && (r < need));
        base += __popcll(eb);
    }
}

// ---------------- selection: 1 wave/row, barrier-free; exact band-repair ----------------
__global__ __launch_bounds__(256) void select_kernel(
    const float* __restrict__ ls, const float* __restrict__ spread,
    const float* __restrict__ vol, const float* __restrict__ X,
    const float* __restrict__ W1, const float* __restrict__ b1,
    const float* __restrict__ W2, const float* __restrict__ b2,
    float* __restrict__ action, float* __restrict__ conf_out)
{
    const int t = threadIdx.x;
    const int l = t & 63;
    const int w = t >> 6;
    const int b = blockIdx.x * 4 + w;
    const size_t base = (size_t)b * N_;

    float rv[8], lsv[8];
    unsigned kr[8];
    bool anyv = false;
    #pragma unroll
    for (int j = 0; j < 8; ++j) {
        int n = l + (j << 6);
        float sp = spread[base + n];
        float vo = vol[base + n];
        bool valid = isfinite(sp) && (sp > 0.f);
        rv[j]  = valid ? (vo / (sp + 1e-8f)) : -INFINITY;
        lsv[j] = ls[base + n];
        anyv |= valid;
        kr[j] = f2key(rv[j]);
    }
    bool allow_all = (__any((int)anyv) == 0);

    unsigned T50; int need50;
    radix_topk(kr, 50, T50, need50);
    bool mem50[8];
    tie_member(kr, T50, need50, mem50);

    float mabs[8];
    unsigned km[8];
    #pragma unroll
    for (int j = 0; j < 8; ++j) {
        bool u = allow_all || mem50[j];
        mabs[j] = u ? fabsf(lsv[j]) : -INFINITY;
        km[j] = f2key(mabs[j]);
    }
    unsigned T10; int need10;
    radix_topk(km, 10, T10, need10);
    bool mem10[8];
    tie_member(km, T10, need10, mem10);
    float b10 = key2f(T10);

    // Z, conf in one butterfly
    float zp = 0.f, cf = -INFINITY;
    #pragma unroll
    for (int j = 0; j < 8; ++j) {
        if (mem10[j]) zp += mabs[j];
        cf = fmaxf(cf, mabs[j]);
    }
    #pragma unroll
    for (int s = 1; s < 64; s <<= 1) {
        zp += __shfl_xor(zp, s, 64);
        cf = fmaxf(cf, __shfl_xor(cf, s, 64));
    }
    float conf = cf;

    // band analysis: how many universe assets within BAND of the 10th value?
    bool confclose = fabsf(conf - 0.05f) <= BANDf;
    bool inband[8];
    int nb = 0;
    #pragma unroll
    for (int j = 0; j < 8; ++j) {
        inband[j] = (mabs[j] != -INFINITY) && (fabsf(mabs[j] - b10) <= BANDf);
        nb += __popcll(__ballot(inband[j]));
    }
    bool redo = (nb >= 2) || confclose;

    if (!redo) {
        float cfin  = isfinite(conf) ? conf : 0.f;
        float scale = (cfin >= 0.05f) ? (1.f / (zp + 1e-8f)) : 0.f;
        #pragma unroll
        for (int j = 0; j < 8; ++j) {
            int n = l + (j << 6);
            action[base + n] = mem10[j] ? lsv[j] * scale : 0.f;
        }
        if (l == 0) conf_out[b] = cfin;
        return;
    }

    // ---- exact recompute of band/conf candidates (wave-cooperative) ----
    const float2* xr2 = (const float2*)&X[base * D_];   // row view: [N][64 float2]
    float4 bb = *(const float4*)&b1[l * 4];
    float4 ww = *(const float4*)&W2[l * 4];
    const float b2v = b2[0];

    #pragma unroll
    for (int j = 0; j < 8; ++j) {
        bool cand = (nb >= 2 && inband[j]) || (confclose && mabs[j] == conf);
        unsigned long long bal = __ballot(cand);
        while (bal) {
            int s = __ffsll((long long)bal) - 1;
            bal &= bal - 1;
            int asset = s + (j << 6);
            float2 x2 = xr2[(size_t)asset * 64 + l];    // lane l holds k=2l,2l+1
            float h0 = 0.f, h1 = 0.f, h2 = 0.f, h3 = 0.f;
            #pragma unroll 16
            for (int kk = 0; kk < D_; ++kk) {
                float xk = __shfl((kk & 1) ? x2.y : x2.x, kk >> 1, 64);
                float4 wv = *(const float4*)&W1[(size_t)kk * H_ + l * 4];
                h0 += xk * wv.x; h1 += xk * wv.y; h2 += xk * wv.z; h3 += xk * wv.w;
            }
            h0 += bb.x; h1 += bb.y; h2 += bb.z; h3 += bb.w;
            float zz = (h0 > 0.f ? h0 : 0.f) * ww.x + (h1 > 0.f ? h1 : 0.f) * ww.y
                     + (h2 > 0.f ? h2 : 0.f) * ww.z + (h3 > 0.f ? h3 : 0.f) * ww.w;
            #pragma unroll
            for (int sh = 1; sh < 64; sh <<= 1) zz += __shfl_xor(zz, sh, 64);
            float val = 1.f / (1.f + expf(-(zz + b2v))) - 0.5f;
            if (l == s) {
                lsv[j]  = val;
                mabs[j] = fabsf(val);
                km[j]   = f2key(mabs[j]);
            }
        }
    }

    // ---- re-rank with exact in-band values ----
    unsigned T10b; int need10b;
    radix_topk(km, 10, T10b, need10b);
    bool mem10b[8];
    tie_member(km, T10b, need10b, mem10b);

    float zx = 0.f, cfx = -INFINITY;
    #pragma unroll
    for (int j = 0; j < 8; ++j) {
        if (mem10b[j]) zx += mabs[j];
        cfx = fmaxf(cfx, mabs[j]);
    }
    #pragma unroll
    for (int s = 1; s < 64; s <<= 1) {
        zx += __shfl_xor(zx, s, 64);
        cfx = fmaxf(cfx, __shfl_xor(cfx, s, 64));
    }
    cfx = isfinite(cfx) ? cfx : 0.f;
    float scale = (cfx >= 0.05f) ? (1.f / (zx + 1e-8f)) : 0.f;
    #pragma unroll
    for (int j = 0; j < 8; ++j) {
        int n = l + (j << 6);
        action[base + n] = mem10b[j] ? lsv[j] * scale : 0.f;
    }
    if (l == 0) conf_out[b] = cfx;
}

extern "C" void kernel_launch(void* const* d_in, const int* in_sizes, int n_in,
                              void* d_out, int out_size, void* d_ws, size_t ws_size,
                              hipStream_t stream)
{
    const float* X  = (const float*)d_in[0];
    const float* sp = (const float*)d_in[1];
    const float* vo = (const float*)d_in[2];
    const float* W1 = (const float*)d_in[3];
    const float* b1 = (const float*)d_in[4];
    const float* W2 = (const float*)d_in[5];
    const float* b2 = (const float*)d_in[6];

    float* action = (float*)d_out;
    float* conf   = action + (size_t)B_ * N_;

    float* ls = (float*)d_ws;                       // 4 MB
    size_t need = (size_t)B_ * N_ * 4 + 2 * (size_t)D_ * H_ * 2;
    short *WpH, *WpL;
    if (ws_size >= need) {
        WpH = (short*)((char*)d_ws + (size_t)B_ * N_ * 4);
        WpL = WpH + (size_t)D_ * H_;
    } else {
        WpH = (short*)(action + (size_t)out_size - 2 * (size_t)D_ * H_ / 2);
        WpL = WpH + (size_t)D_ * H_;
    }

    hipLaunchKernelGGL(pack_w, dim3(16), dim3(256), 0, stream, W1, WpH, WpL);
    hipLaunchKernelGGL(mlp_mfma, dim3(512), dim3(512), 0, stream,
                       X, WpH, WpL, b1, W2, b2, ls);
    hipLaunchKernelGGL(select_kernel, dim3(B_ / 4), dim3(256), 0, stream,
                       ls, sp, vo, X, W1, b1, W2, b2, action, conf);
}

// Round 7
// 462.100 us; speedup vs baseline: 1.2631x; 1.0035x over previous
//
#include <hip/hip_runtime.h>
#include <hip/hip_bf16.h>
#include <math.h>

#define B_ 2048
#define N_ 512
#define D_ 128
#define H_ 256
#define BANDf 2e-4f   // repair band: >= 2x worst-case bf16x3 score error (~1e-5..5e-5)

typedef __attribute__((ext_vector_type(8))) short bf16x8;
typedef __attribute__((ext_vector_type(4))) short short4v;
typedef __attribute__((ext_vector_type(4))) float f32x4;

__device__ __forceinline__ short f2bf(float x) {          // rne f32 -> bf16
    unsigned u = __float_as_uint(x);
    u = u + 0x7fffu + ((u >> 16) & 1u);
    return (short)(u >> 16);
}
__device__ __forceinline__ float bf2f(short h) {
    return __uint_as_float(((unsigned)(unsigned short)h) << 16);
}

// ---------------- W1 pre-pack: fragment-ordered bf16 hi/lo ----------------
// B-frag (16x16x32): lane l holds B[k = ks*32 + (l>>4)*8 + j][n = nf*16 + (l&15)]
__global__ __launch_bounds__(256) void pack_w(const float* __restrict__ W1,
                                              short* __restrict__ WpH,
                                              short* __restrict__ WpL)
{
    int tid = blockIdx.x * 256 + threadIdx.x;   // 0..4095
    int l  = tid & 63;
    int ks = (tid >> 6) & 3;
    int nf = tid >> 8;
    int n  = nf * 16 + (l & 15);
    int kb = ks * 32 + ((l >> 4) << 3);
    bf16x8 hi, lo;
    #pragma unroll
    for (int j = 0; j < 8; ++j) {
        float w = W1[(size_t)(kb + j) * H_ + n];
        short h = f2bf(w);
        hi[j] = h;
        lo[j] = f2bf(w - bf2f(h));
    }
    *(bf16x8*)&WpH[(size_t)tid * 8] = hi;
    *(bf16x8*)&WpL[(size_t)tid * 8] = lo;
}

// ---------------- MLP via bf16x3 MFMA — 8-wave blocks, B fully VGPR-resident ----------------
// 512 blocks x 512 thr (8 waves) = 2 blocks/CU, 16 waves/CU. Block tile 64 rows x 256 cols.
// Wave wn owns cols wn*32..+31 (q=0..1), rows 0..63 (mf=0..3). acc = 32 AGPR; B = 64 VGPR.
__global__ __launch_bounds__(512, 4) void mlp_mfma(
    const float* __restrict__ X, const short* __restrict__ WpH,
    const short* __restrict__ WpL, const float* __restrict__ b1,
    const float* __restrict__ W2, const float* __restrict__ b2,
    float* __restrict__ ls)
{
    __shared__ short Xh[64 * 128];
    __shared__ short Xl[64 * 128];
    __shared__ float zl[512];

    const int t    = threadIdx.x;
    const int lane = t & 63;
    const int wn   = t >> 6;

    const bf16x8* WH = (const bf16x8*)WpH;
    const bf16x8* WL = (const bf16x8*)WpL;

    const int GRID = 512;
    const int NT = (B_ * N_ / 64) / GRID;       // 32 tiles per block
    int tile = blockIdx.x;

    float4 pf[4];                               // prefetch registers (16 VGPR)
    {
        const float4* Xg = (const float4*)(X + (size_t)tile * 64 * D_);
        #pragma unroll
        for (int i = 0; i < 4; ++i) pf[i] = Xg[t + i * 512];
    }

    // B fully resident: hi+lo, 2 cols x 4 ks = 16 frags = 64 VGPR (one-time L2 read)
    bf16x8 Bh[2][4], Bl[2][4];
    #pragma unroll
    for (int q = 0; q < 2; ++q)
        #pragma unroll
        for (int ks = 0; ks < 4; ++ks) {
            Bh[q][ks] = WH[((wn * 2 + q) * 4 + ks) * 64 + lane];
            Bl[q][ks] = WL[((wn * 2 + q) * 4 + ks) * 64 + lane];
        }

    float b1v[2], w2v[2];
    #pragma unroll
    for (int q = 0; q < 2; ++q) {
        int c = wn * 32 + q * 16 + (lane & 15);
        b1v[q] = b1[c];
        w2v[q] = W2[c];
    }
    const float b2v = b2[0];

    size_t m_prev = 0;

    for (int it = 0; it < NT; ++it) {
        const size_t m0 = (size_t)tile * 64;
        const int ntile = tile + GRID;

        __syncthreads();                        // (a) LDS X free; zl(prev) complete

        if (it > 0 && t < 64) {                 // deferred epilogue (reads zl only)
            float z = b2v;
            #pragma unroll
            for (int w8 = 0; w8 < 8; ++w8) z += zl[w8 * 64 + t];
            ls[m_prev + t] = 1.f / (1.f + expf(-z)) - 0.5f;
        }

        // convert pf -> LDS (waits on loads issued last iteration)
        #pragma unroll
        for (int i = 0; i < 4; ++i) {
            int f = t + i * 512;
            int row = f >> 5, k0 = (f & 31) << 2;
            float xv[4] = {pf[i].x, pf[i].y, pf[i].z, pf[i].w};
            short4v hv, lv;
            #pragma unroll
            for (int j = 0; j < 4; ++j) {
                short h = f2bf(xv[j]);
                hv[j] = h;
                lv[j] = f2bf(xv[j] - bf2f(h));
            }
            int sidx = (row * 128 + k0) ^ ((row & 7) << 3);
            *(short4v*)&Xh[sidx] = hv;
            *(short4v*)&Xl[sidx] = lv;
        }

        if (it + 1 < NT) {                      // issue next tile's X loads (~full tile of cover)
            const float4* Xg = (const float4*)(X + (size_t)ntile * 64 * D_);
            #pragma unroll
            for (int i = 0; i < 4; ++i) pf[i] = Xg[t + i * 512];
        }

        __syncthreads();                        // (b) X tile visible

        f32x4 acc[4][2];
        #pragma unroll
        for (int mf = 0; mf < 4; ++mf)
            #pragma unroll
            for (int q = 0; q < 2; ++q)
                acc[mf][q] = (f32x4){0.f, 0.f, 0.f, 0.f};

        #pragma unroll
        for (int ks = 0; ks < 4; ++ks) {
            #pragma unroll
            for (int mf = 0; mf < 4; ++mf) {
                int r = mf * 16 + (lane & 15);
                int sidx = (r * 128 + ks * 32 + ((lane >> 4) << 3)) ^ ((r & 7) << 3);
                bf16x8 Ah = *(const bf16x8*)&Xh[sidx];
                bf16x8 Al = *(const bf16x8*)&Xl[sidx];
                #pragma unroll
                for (int q = 0; q < 2; ++q) {
                    acc[mf][q] = __builtin_amdgcn_mfma_f32_16x16x32_bf16(Ah, Bh[q][ks], acc[mf][q], 0, 0, 0);
                    acc[mf][q] = __builtin_amdgcn_mfma_f32_16x16x32_bf16(Al, Bh[q][ks], acc[mf][q], 0, 0, 0);
                    acc[mf][q] = __builtin_amdgcn_mfma_f32_16x16x32_bf16(Ah, Bl[q][ks], acc[mf][q], 0, 0, 0);
                }
            }
        }

        // z partials -> zl (read after next barrier (a))
        #pragma unroll
        for (int mf = 0; mf < 4; ++mf) {
            #pragma unroll
            for (int i = 0; i < 4; ++i) {
                float zz = 0.f;
                #pragma unroll
                for (int q = 0; q < 2; ++q) {
                    float h = acc[mf][q][i] + b1v[q];
                    h = h > 0.f ? h : 0.f;
                    zz += h * w2v[q];
                }
                zz += __shfl_xor(zz, 1, 64);
                zz += __shfl_xor(zz, 2, 64);
                zz += __shfl_xor(zz, 4, 64);
                zz += __shfl_xor(zz, 8, 64);
                if ((lane & 15) == 0) zl[wn * 64 + mf * 16 + ((lane >> 4) << 2) + i] = zz;
            }
        }

        m_prev = m0;
        tile = ntile;
    }

    __syncthreads();
    if (t < 64) {
        float z = b2v;
        #pragma unroll
        for (int w8 = 0; w8 < 8; ++w8) z += zl[w8 * 64 + t];
        ls[m_prev + t] = 1.f / (1.f + expf(-z)) - 0.5f;
    }
}

// ---------------- radix-select machinery (ballot-based, no DS ops) ----------------
__device__ __forceinline__ unsigned f2key(float f) {      // monotone float->uint
    unsigned u = __float_as_uint(f);
    return (u & 0x80000000u) ? ~u : (u | 0x80000000u);
}
__device__ __forceinline__ float key2f(unsigned k) {
    return __uint_as_float((k & 0x80000000u) ? (k & 0x7fffffffu) : ~k);
}
__device__ __forceinline__ int lane_lt_count(unsigned long long m) {
    return __builtin_amdgcn_mbcnt_hi((unsigned)(m >> 32),
           __builtin_amdgcn_mbcnt_lo((unsigned)m, 0));
}

__device__ __forceinline__ void radix_topk(const unsigned (&key)[8], int k,
                                           unsigned &T, int &need)
{
    unsigned prefix = 0, maskhi = 0;
    int kk = k;
    for (int bit = 31; bit >= 0; --bit) {
        unsigned b = 1u << bit;
        int cnt1 = 0;
        #pragma unroll
        for (int j = 0; j < 8; ++j) {
            bool one = ((key[j] & maskhi) == prefix) && (key[j] & b);
            cnt1 += __popcll(__ballot(one));
        }
        if (cnt1 >= kk) prefix |= b; else kk -= cnt1;
        maskhi |= b;
    }
    T = prefix; need = kk;
}

// membership, lowest-global-index tiebreak (slot n = l + 64*j => rank by (j, lane))
__device__ __forceinline__ void tie_member(const unsigned (&key)[8], unsigned T,
                                           int need, bool (&mem)[8])
{
    int base = 0;
    #pragma unroll
    for (int j = 0; j < 8; ++j) {
        unsigned long long eb = __ballot(key[j] == T);
        int r = base + lane_lt_count(eb);
        mem[j] = (key[j] > T) || ((key[j] == T) && (r < need));
        base += __popcll(eb);
    }
}

// ---------------- selection: 1 wave/row, barrier-free; exact band-repair ----------------
__global__ __launch_bounds__(256) void select_kernel(
    const float* __restrict__ ls, const float* __restrict__ spread,
    const float* __restrict__ vol, const float* __restrict__ X,
    const float* __restrict__ W1, const float* __restrict__ b1,
    const float* __restrict__ W2, const float* __restrict__ b2,
    float* __restrict__ action, float* __restrict__ conf_out)
{
    const int t = threadIdx.x;
    const int l = t & 63;
    const int w = t >> 6;
    const int b = blockIdx.x * 4 + w;
    const size_t base = (size_t)b * N_;

    float rv[8], lsv[8];
    unsigned kr[8];
    bool anyv = false;
    #pragma unroll
    for (int j = 0; j < 8; ++j) {
        int n = l + (j << 6);
        float sp = spread[base + n];
        float vo = vol[base + n];
        bool valid = isfinite(sp) && (sp > 0.f);
        rv[j]  = valid ? (vo / (sp + 1e-8f)) : -INFINITY;
        lsv[j] = ls[base + n];
        anyv |= valid;
        kr[j] = f2key(rv[j]);
    }
    bool allow_all = (__any((int)anyv) == 0);

    unsigned T50; int need50;
    radix_topk(kr, 50, T50, need50);
    bool mem50[8];
    tie_member(kr, T50, need50, mem50);

    float mabs[8];
    unsigned km[8];
    #pragma unroll
    for (int j = 0; j < 8; ++j) {
        bool u = allow_all || mem50[j];
        mabs[j] = u ? fabsf(lsv[j]) : -INFINITY;
        km[j] = f2key(mabs[j]);
    }
    unsigned T10; int need10;
    radix_topk(km, 10, T10, need10);
    bool mem10[8];
    tie_member(km, T10, need10, mem10);
    float b10 = key2f(T10);

    // Z, conf in one butterfly
    float zp = 0.f, cf = -INFINITY;
    #pragma unroll
    for (int j = 0; j < 8; ++j) {
        if (mem10[j]) zp += mabs[j];
        cf = fmaxf(cf, mabs[j]);
    }
    #pragma unroll
    for (int s = 1; s < 64; s <<= 1) {
        zp += __shfl_xor(zp, s, 64);
        cf = fmaxf(cf, __shfl_xor(cf, s, 64));
    }
    float conf = cf;

    // band analysis: how many universe assets within BAND of the 10th value?
    bool confclose = fabsf(conf - 0.05f) <= BANDf;
    bool inband[8];
    int nb = 0;
    #pragma unroll
    for (int j = 0; j < 8; ++j) {
        inband[j] = (mabs[j] != -INFINITY) && (fabsf(mabs[j] - b10) <= BANDf);
        nb += __popcll(__ballot(inband[j]));
    }
    bool redo = (nb >= 2) || confclose;

    if (!redo) {
        float cfin  = isfinite(conf) ? conf : 0.f;
        float scale = (cfin >= 0.05f) ? (1.f / (zp + 1e-8f)) : 0.f;
        #pragma unroll
        for (int j = 0; j < 8; ++j) {
            int n = l + (j << 6);
            action[base + n] = mem10[j] ? lsv[j] * scale : 0.f;
        }
        if (l == 0) conf_out[b] = cfin;
        return;
    }

    // ---- exact recompute of band/conf candidates (wave-cooperative) ----
    const float2* xr2 = (const float2*)&X[base * D_];   // row view: [N][64 float2]
    float4 bb = *(const float4*)&b1[l * 4];
    float4 ww = *(const float4*)&W2[l * 4];
    const float b2v = b2[0];

    #pragma unroll
    for (int j = 0; j < 8; ++j) {
        bool cand = (nb >= 2 && inband[j]) || (confclose && mabs[j] == conf);
        unsigned long long bal = __ballot(cand);
        while (bal) {
            int s = __ffsll((long long)bal) - 1;
            bal &= bal - 1;
            int asset = s + (j << 6);
            float2 x2 = xr2[(size_t)asset * 64 + l];    // lane l holds k=2l,2l+1
            float h0 = 0.f, h1 = 0.f, h2 = 0.f, h3 = 0.f;
            #pragma unroll 16
            for (int kk = 0; kk < D_; ++kk) {
                float xk = __shfl((kk & 1) ? x2.y : x2.x, kk >> 1, 64);
                float4 wv = *(const float4*)&W1[(size_t)kk * H_ + l * 4];
                h0 += xk * wv.x; h1 += xk * wv.y; h2 += xk * wv.z; h3 += xk * wv.w;
            }
            h0 += bb.x; h1 += bb.y; h2 += bb.z; h3 += bb.w;
            float zz = (h0 > 0.f ? h0 : 0.f) * ww.x + (h1 > 0.f ? h1 : 0.f) * ww.y
                     + (h2 > 0.f ? h2 : 0.f) * ww.z + (h3 > 0.f ? h3 : 0.f) * ww.w;
            #pragma unroll
            for (int sh = 1; sh < 64; sh <<= 1) zz += __shfl_xor(zz, sh, 64);
            float val = 1.f / (1.f + expf(-(zz + b2v))) - 0.5f;
            if (l == s) {
                lsv[j]  = val;
                mabs[j] = fabsf(val);
                km[j]   = f2key(mabs[j]);
            }
        }
    }

    // ---- re-rank with exact in-band values ----
    unsigned T10b; int need10b;
    radix_topk(km, 10, T10b, need10b);
    bool mem10b[8];
    tie_member(km, T10b, need10b, mem10b);

    float zx = 0.f, cfx = -INFINITY;
    #pragma unroll
    for (int j = 0; j < 8; ++j) {
        if (mem10b[j]) zx += mabs[j];
        cfx = fmaxf(cfx, mabs[j]);
    }
    #pragma unroll
    for (int s = 1; s < 64; s <<= 1) {
        zx += __shfl_xor(zx, s, 64);
        cfx = fmaxf(cfx, __shfl_xor(cfx, s, 64));
    }
    cfx = isfinite(cfx) ? cfx : 0.f;
    float scale = (cfx >= 0.05f) ? (1.f / (zx + 1e-8f)) : 0.f;
    #pragma unroll
    for (int j = 0; j < 8; ++j) {
        int n = l + (j << 6);
        action[base + n] = mem10b[j] ? lsv[j] * scale : 0.f;
    }
    if (l == 0) conf_out[b] = cfx;
}

extern "C" void kernel_launch(void* const* d_in, const int* in_sizes, int n_in,
                              void* d_out, int out_size, void* d_ws, size_t ws_size,
                              hipStream_t stream)
{
    const float* X  = (const float*)d_in[0];
    const float* sp = (const float*)d_in[1];
    const float* vo = (const float*)d_in[2];
    const float* W1 = (const float*)d_in[3];
    const float* b1 = (const float*)d_in[4];
    const float* W2 = (const float*)d_in[5];
    const float* b2 = (const float*)d_in[6];

    float* action = (float*)d_out;
    float* conf   = action + (size_t)B_ * N_;

    float* ls = (float*)d_ws;                       // 4 MB
    size_t need = (size_t)B_ * N_ * 4 + 2 * (size_t)D_ * H_ * 2;
    short *WpH, *WpL;
    if (ws_size >= need) {
        WpH = (short*)((char*)d_ws + (size_t)B_ * N_ * 4);
        WpL = WpH + (size_t)D_ * H_;
    } else {
        WpH = (short*)(action + (size_t)out_size - 2 * (size_t)D_ * H_ / 2);
        WpL = WpH + (size_t)D_ * H_;
    }

    hipLaunchKernelGGL(pack_w, dim3(16), dim3(256), 0, stream, W1, WpH, WpL);
    hipLaunchKernelGGL(mlp_mfma, dim3(512), dim3(512), 0, stream,
                       X, WpH, WpL, b1, W2, b2, ls);
    hipLaunchKernelGGL(select_kernel, dim3(B_ / 4), dim3(256), 0, stream,
                       ls, sp, vo, X, W1, b1, W2, b2, action, conf);
}

// Round 9
// 423.566 us; speedup vs baseline: 1.3780x; 1.0910x over previous
//
#include <hip/hip_runtime.h>
#include <hip/hip_bf16.h>
#include <math.h>

#define B_ 2048
#define N_ 512
#define D_ 128
#define H_ 256
#define BANDf 2e-4f   // repair band: >= 2x worst-case bf16x3 score error (~1e-5..5e-5)

typedef __attribute__((ext_vector_type(8))) short bf16x8;
typedef __attribute__((ext_vector_type(4))) float f32x4;

__device__ __forceinline__ short f2bf(float x) {          // rne f32 -> bf16
    unsigned u = __float_as_uint(x);
    u = u + 0x7fffu + ((u >> 16) & 1u);
    return (short)(u >> 16);
}
__device__ __forceinline__ float bf2f(short h) {
    return __uint_as_float(((unsigned)(unsigned short)h) << 16);
}
__device__ __forceinline__ unsigned cvt_pk_bf16(float a, float b) { // [lo]=bf(a) [hi]=bf(b)
    unsigned r;
    asm("v_cvt_pk_bf16_f32 %0, %1, %2" : "=v"(r) : "v"(a), "v"(b));
    return r;
}
// DPP row_shr add: zz += lane(i-K within 16-lane row), 0-filled; K must be constexpr
template<int K>
__device__ __forceinline__ float dpp_shr_add(float zz) {
    int s = __builtin_amdgcn_update_dpp(0, __float_as_int(zz), 0x110 | K, 0xf, 0xf, true);
    return zz + __int_as_float(s);
}

// ---------------- W1 pre-pack: fragment-ordered bf16 hi/lo ----------------
// B-frag (16x16x32): lane l holds B[k = ks*32 + (l>>4)*8 + j][n = nf*16 + (l&15)]
__global__ __launch_bounds__(256) void pack_w(const float* __restrict__ W1,
                                              short* __restrict__ WpH,
                                              short* __restrict__ WpL)
{
    int tid = blockIdx.x * 256 + threadIdx.x;   // 0..4095
    int l  = tid & 63;
    int ks = (tid >> 6) & 3;
    int nf = tid >> 8;
    int n  = nf * 16 + (l & 15);
    int kb = ks * 32 + ((l >> 4) << 3);
    bf16x8 hi, lo;
    #pragma unroll
    for (int j = 0; j < 8; ++j) {
        float w = W1[(size_t)(kb + j) * H_ + n];
        short h = f2bf(w);
        hi[j] = h;
        lo[j] = f2bf(w - bf2f(h));
    }
    *(bf16x8*)&WpH[(size_t)tid * 8] = hi;
    *(bf16x8*)&WpL[(size_t)tid * 8] = lo;
}

// ---------------- MLP via bf16x3 MFMA — 4 waves, 64 cols/wave, B fully resident ----------------
// 512 blocks x 256 thr = 2 blocks/CU. Block tile 64 rows x 256 cols, NT=32 tiles/block.
// Wave wn owns cols wn*64..+63 (q=0..3). acc 64 AGPR, B 128 VGPR, pf 32 VGPR.
__global__ __launch_bounds__(256, 2) void mlp_mfma(
    const float* __restrict__ X, const short* __restrict__ WpH,
    const short* __restrict__ WpL, const float* __restrict__ b1,
    const float* __restrict__ W2, const float* __restrict__ b2,
    float* __restrict__ ls)
{
    __shared__ short Xh[64 * 128];
    __shared__ short Xl[64 * 128];
    __shared__ float zl[256];

    const int t    = threadIdx.x;
    const int lane = t & 63;
    const int wn   = t >> 6;

    const bf16x8* WH = (const bf16x8*)WpH;
    const bf16x8* WL = (const bf16x8*)WpL;

    const int GRID = 512;
    const int NT = (B_ * N_ / 64) / GRID;       // 32 tiles per block
    int tile = blockIdx.x;

    float4 pf[8];                               // prefetch registers (32 VGPR)
    {
        const float4* Xg = (const float4*)(X + (size_t)tile * 64 * D_);
        #pragma unroll
        for (int i = 0; i < 8; ++i) pf[i] = Xg[t + i * 256];
    }

    // B fully resident: hi+lo, 4 cols x 4 ks = 32 frags = 128 VGPR (one-time read)
    bf16x8 Bh[4][4], Bl[4][4];
    #pragma unroll
    for (int q = 0; q < 4; ++q)
        #pragma unroll
        for (int ks = 0; ks < 4; ++ks) {
            Bh[q][ks] = WH[((wn * 4 + q) * 4 + ks) * 64 + lane];
            Bl[q][ks] = WL[((wn * 4 + q) * 4 + ks) * 64 + lane];
        }

    float b1v[4], w2v[4];
    #pragma unroll
    for (int q = 0; q < 4; ++q) {
        int c = wn * 64 + q * 16 + (lane & 15);
        b1v[q] = b1[c];
        w2v[q] = W2[c];
    }
    const float b2v = b2[0];

    size_t m_prev = 0;

    for (int it = 0; it < NT; ++it) {
        const size_t m0 = (size_t)tile * 64;
        const int ntile = tile + GRID;

        __syncthreads();                        // (a) LDS X free; zl(prev) complete

        if (it > 0 && t < 64) {                 // deferred epilogue (reads zl only)
            float z = zl[t] + zl[64 + t] + zl[128 + t] + zl[192 + t] + b2v;
            ls[m_prev + t] = 1.f / (1.f + expf(-z)) - 0.5f;
        }

        // convert pf -> LDS via hw packed cvt (3 VALU/elem)
        #pragma unroll
        for (int i = 0; i < 8; ++i) {
            int f = t + i * 256;
            int row = f >> 5, k0 = (f & 31) << 2;
            unsigned h01 = cvt_pk_bf16(pf[i].x, pf[i].y);
            unsigned h23 = cvt_pk_bf16(pf[i].z, pf[i].w);
            float l0 = pf[i].x - __uint_as_float(h01 << 16);
            float l1 = pf[i].y - __uint_as_float(h01 & 0xffff0000u);
            float l2 = pf[i].z - __uint_as_float(h23 << 16);
            float l3 = pf[i].w - __uint_as_float(h23 & 0xffff0000u);
            unsigned lo01 = cvt_pk_bf16(l0, l1);
            unsigned lo23 = cvt_pk_bf16(l2, l3);
            int sidx = (row * 128 + k0) ^ ((row & 7) << 3);
            *(uint2*)&Xh[sidx] = make_uint2(h01, h23);
            *(uint2*)&Xl[sidx] = make_uint2(lo01, lo23);
        }

        if (it + 1 < NT) {                      // issue next tile's X loads (full tile of cover)
            const float4* Xg = (const float4*)(X + (size_t)ntile * 64 * D_);
            #pragma unroll
            for (int i = 0; i < 8; ++i) pf[i] = Xg[t + i * 256];
        }

        __syncthreads();                        // (b) X tile visible

        f32x4 acc[4][4];
        #pragma unroll
        for (int mf = 0; mf < 4; ++mf)
            #pragma unroll
            for (int q = 0; q < 4; ++q)
                acc[mf][q] = (f32x4){0.f, 0.f, 0.f, 0.f};

        #pragma unroll
        for (int ks = 0; ks < 4; ++ks) {
            #pragma unroll
            for (int mf = 0; mf < 4; ++mf) {
                int r = mf * 16 + (lane & 15);
                int sidx = (r * 128 + ks * 32 + ((lane >> 4) << 3)) ^ ((r & 7) << 3);
                bf16x8 Ah = *(const bf16x8*)&Xh[sidx];
                bf16x8 Al = *(const bf16x8*)&Xl[sidx];
                #pragma unroll
                for (int q = 0; q < 4; ++q) {
                    acc[mf][q] = __builtin_amdgcn_mfma_f32_16x16x32_bf16(Ah, Bh[q][ks], acc[mf][q], 0, 0, 0);
                    acc[mf][q] = __builtin_amdgcn_mfma_f32_16x16x32_bf16(Al, Bh[q][ks], acc[mf][q], 0, 0, 0);
                    acc[mf][q] = __builtin_amdgcn_mfma_f32_16x16x32_bf16(Ah, Bl[q][ks], acc[mf][q], 0, 0, 0);
                }
            }
        }

        // z partials -> zl via DPP row-reduce (VALU pipe only, no DS ops)
        #pragma unroll
        for (int mf = 0; mf < 4; ++mf) {
            #pragma unroll
            for (int i = 0; i < 4; ++i) {
                float zz = 0.f;
                #pragma unroll
                for (int q = 0; q < 4; ++q) {
                    float h = acc[mf][q][i] + b1v[q];
                    h = h > 0.f ? h : 0.f;
                    zz += h * w2v[q];
                }
                zz = dpp_shr_add<1>(zz);
                zz = dpp_shr_add<2>(zz);
                zz = dpp_shr_add<4>(zz);
                zz = dpp_shr_add<8>(zz);        // lane (l&15)==15 holds row sum
                if ((lane & 15) == 15) zl[wn * 64 + mf * 16 + ((lane >> 4) << 2) + i] = zz;
            }
        }

        m_prev = m0;
        tile = ntile;
    }

    __syncthreads();
    if (t < 64) {
        float z = zl[t] + zl[64 + t] + zl[128 + t] + zl[192 + t] + b2v;
        ls[m_prev + t] = 1.f / (1.f + expf(-z)) - 0.5f;
    }
}

// ---------------- radix-select machinery (ballot-based, no DS ops) ----------------
__device__ __forceinline__ unsigned f2key(float f) {      // monotone float->uint
    unsigned u = __float_as_uint(f);
    return (u & 0x80000000u) ? ~u : (u | 0x80000000u);
}
__device__ __forceinline__ float key2f(unsigned k) {
    return __uint_as_float((k & 0x80000000u) ? (k & 0x7fffffffu) : ~k);
}
__device__ __forceinline__ int lane_lt_count(unsigned long long m) {
    return __builtin_amdgcn_mbcnt_hi((unsigned)(m >> 32),
           __builtin_amdgcn_mbcnt_lo((unsigned)m, 0));
}

__device__ __forceinline__ void radix_topk(const unsigned (&key)[8], int k,
                                           unsigned &T, int &need)
{
    unsigned prefix = 0, maskhi = 0;
    int kk = k;
    for (int bit = 31; bit >= 0; --bit) {
        unsigned b = 1u << bit;
        int cnt1 = 0;
        #pragma unroll
        for (int j = 0; j < 8; ++j) {
            bool one = ((key[j] & maskhi) == prefix) && (key[j] & b);
            cnt1 += __popcll(__ballot(one));
        }
        if (cnt1 >= kk) prefix |= b; else kk -= cnt1;
        maskhi |= b;
    }
    T = prefix; need = kk;
}

// membership, lowest-global-index tiebreak (slot n = l + 64*j => rank by (j, lane))
__device__ __forceinline__ void tie_member(const unsigned (&key)[8], unsigned T,
                                           int need, bool (&mem)[8])
{
    int base = 0;
    #pragma unroll
    for (int j = 0; j < 8; ++j) {
        unsigned long long eb = __ballot(key[j] == T);
        int r = base + lane_lt_count(eb);
        mem[j] = (key[j] > T) || ((key[j] == T) && (r < need));
        base += __popcll(eb);
    }
}

// ---------------- selection: 1 wave/row, barrier-free; exact band-repair ----------------
__global__ __launch_bounds__(256) void select_kernel(
    const float* __restrict__ ls, const float* __restrict__ spread,
    const float* __restrict__ vol, const float* __restrict__ X,
    const float* __restrict__ W1, const float* __restrict__ b1,
    const float* __restrict__ W2, const float* __restrict__ b2,
    float* __restrict__ action, float* __restrict__ conf_out)
{
    const int t = threadIdx.x;
    const int l = t & 63;
    const int w = t >> 6;
    const int b = blockIdx.x * 4 + w;
    const size_t base = (size_t)b * N_;

    float rv[8], lsv[8];
    unsigned kr[8];
    bool anyv = false;
    #pragma unroll
    for (int j = 0; j < 8; ++j) {
        int n = l + (j << 6);
        float sp = spread[base + n];
        float vo = vol[base + n];
        bool valid = isfinite(sp) && (sp > 0.f);
        rv[j]  = valid ? (vo / (sp + 1e-8f)) : -INFINITY;
        lsv[j] = ls[base + n];
        anyv |= valid;
        kr[j] = f2key(rv[j]);
    }
    bool allow_all = (__any((int)anyv) == 0);

    unsigned T50; int need50;
    radix_topk(kr, 50, T50, need50);
    bool mem50[8];
    tie_member(kr, T50, need50, mem50);

    float mabs[8];
    unsigned km[8];
    #pragma unroll
    for (int j = 0; j < 8; ++j) {
        bool u = allow_all || mem50[j];
        mabs[j] = u ? fabsf(lsv[j]) : -INFINITY;
        km[j] = f2key(mabs[j]);
    }
    unsigned T10; int need10;
    radix_topk(km, 10, T10, need10);
    bool mem10[8];
    tie_member(km, T10, need10, mem10);
    float b10 = key2f(T10);

    // Z, conf in one butterfly
    float zp = 0.f, cf = -INFINITY;
    #pragma unroll
    for (int j = 0; j < 8; ++j) {
        if (mem10[j]) zp += mabs[j];
        cf = fmaxf(cf, mabs[j]);
    }
    #pragma unroll
    for (int s = 1; s < 64; s <<= 1) {
        zp += __shfl_xor(zp, s, 64);
        cf = fmaxf(cf, __shfl_xor(cf, s, 64));
    }
    float conf = cf;

    // band analysis: how many universe assets within BAND of the 10th value?
    bool confclose = fabsf(conf - 0.05f) <= BANDf;
    bool inband[8];
    int nb = 0;
    #pragma unroll
    for (int j = 0; j < 8; ++j) {
        inband[j] = (mabs[j] != -INFINITY) && (fabsf(mabs[j] - b10) <= BANDf);
        nb += __popcll(__ballot(inband[j]));
    }
    bool redo = (nb >= 2) || confclose;

    if (!redo) {
        float cfin  = isfinite(conf) ? conf : 0.f;
        float scale = (cfin >= 0.05f) ? (1.f / (zp + 1e-8f)) : 0.f;
        #pragma unroll
        for (int j = 0; j < 8; ++j) {
            int n = l + (j << 6);
            action[base + n] = mem10[j] ? lsv[j] * scale : 0.f;
        }
        if (l == 0) conf_out[b] = cfin;
        return;
    }

    // ---- exact recompute of band/conf candidates (wave-cooperative) ----
    const float2* xr2 = (const float2*)&X[base * D_];   // row view: [N][64 float2]
    float4 bb = *(const float4*)&b1[l * 4];
    float4 ww = *(const float4*)&W2[l * 4];
    const float b2v = b2[0];

    #pragma unroll
    for (int j = 0; j < 8; ++j) {
        bool cand = (nb >= 2 && inband[j]) || (confclose && mabs[j] == conf);
        unsigned long long bal = __ballot(cand);
        while (bal) {
            int s = __ffsll((long long)bal) - 1;
            bal &= bal - 1;
            int asset = s + (j << 6);
            float2 x2 = xr2[(size_t)asset * 64 + l];    // lane l holds k=2l,2l+1
            float h0 = 0.f, h1 = 0.f, h2 = 0.f, h3 = 0.f;
            #pragma unroll 16
            for (int kk = 0; kk < D_; ++kk) {
                float xk = __shfl((kk & 1) ? x2.y : x2.x, kk >> 1, 64);
                float4 wv = *(const float4*)&W1[(size_t)kk * H_ + l * 4];
                h0 += xk * wv.x; h1 += xk * wv.y; h2 += xk * wv.z; h3 += xk * wv.w;
            }
            h0 += bb.x; h1 += bb.y; h2 += bb.z; h3 += bb.w;
            float zz = (h0 > 0.f ? h0 : 0.f) * ww.x + (h1 > 0.f ? h1 : 0.f) * ww.y
                     + (h2 > 0.f ? h2 : 0.f) * ww.z + (h3 > 0.f ? h3 : 0.f) * ww.w;
            #pragma unroll
            for (int sh = 1; sh < 64; sh <<= 1) zz += __shfl_xor(zz, sh, 64);
            float val = 1.f / (1.f + expf(-(zz + b2v))) - 0.5f;
            if (l == s) {
                lsv[j]  = val;
                mabs[j] = fabsf(val);
                km[j]   = f2key(mabs[j]);
            }
        }
    }

    // ---- re-rank with exact in-band values ----
    unsigned T10b; int need10b;
    radix_topk(km, 10, T10b, need10b);
    bool mem10b[8];
    tie_member(km, T10b, need10b, mem10b);

    float zx = 0.f, cfx = -INFINITY;
    #pragma unroll
    for (int j = 0; j < 8; ++j) {
        if (mem10b[j]) zx += mabs[j];
        cfx = fmaxf(cfx, mabs[j]);
    }
    #pragma unroll
    for (int s = 1; s < 64; s <<= 1) {
        zx += __shfl_xor(zx, s, 64);
        cfx = fmaxf(cfx, __shfl_xor(cfx, s, 64));
    }
    cfx = isfinite(cfx) ? cfx : 0.f;
    float scale = (cfx >= 0.05f) ? (1.f / (zx + 1e-8f)) : 0.f;
    #pragma unroll
    for (int j = 0; j < 8; ++j) {
        int n = l + (j << 6);
        action[base + n] = mem10b[j] ? lsv[j] * scale : 0.f;
    }
    if (l == 0) conf_out[b] = cfx;
}

extern "C" void kernel_launch(void* const* d_in, const int* in_sizes, int n_in,
                              void* d_out, int out_size, void* d_ws, size_t ws_size,
                              hipStream_t stream)
{
    const float* X  = (const float*)d_in[0];
    const float* sp = (const float*)d_in[1];
    const float* vo = (const float*)d_in[2];
    const float* W1 = (const float*)d_in[3];
    const float* b1 = (const float*)d_in[4];
    const float* W2 = (const float*)d_in[5];
    const float* b2 = (const float*)d_in[6];

    float* action = (float*)d_out;
    float* conf   = action + (size_t)B_ * N_;

    float* ls = (float*)d_ws;                       // 4 MB
    size_t need = (size_t)B_ * N_ * 4 + 2 * (size_t)D_ * H_ * 2;
    short *WpH, *WpL;
    if (ws_size >= need) {
        WpH = (short*)((char*)d_ws + (size_t)B_ * N_ * 4);
        WpL = WpH + (size_t)D_ * H_;
    } else {
        WpH = (short*)(action + (size_t)out_size - 2 * (size_t)D_ * H_ / 2);
        WpL = WpH + (size_t)D_ * H_;
    }

    hipLaunchKernelGGL(pack_w, dim3(16), dim3(256), 0, stream, W1, WpH, WpL);
    hipLaunchKernelGGL(mlp_mfma, dim3(512), dim3(256), 0, stream,
                       X, WpH, WpL, b1, W2, b2, ls);
    hipLaunchKernelGGL(select_kernel, dim3(B_ / 4), dim3(256), 0, stream,
                       ls, sp, vo, X, W1, b1, W2, b2, action, conf);
}